// Round 6
// baseline (167.474 us; speedup 1.0000x reference)
//
#include <hip/hip_runtime.h>
#include <hip/hip_bf16.h>

// SelfAttentionLayer: B=64, N=1024, C=128, D=64
// R5: attn 64 q/wave (halves K/V L2 traffic to 256 MB), kf ping-pong (no mov
// copies), LDS-vectorized epilogue. qkv: single LDS transpose pass makes all
// global stores coalesced b128 (was 32 scalar b16 + 2 b128 per thread).

#define Bsz 64
#define Nsz 1024
#define Csz 128
#define Dsz 64

typedef __attribute__((ext_vector_type(8))) short short8;
typedef __attribute__((ext_vector_type(4))) float f32x4;

__device__ __forceinline__ unsigned short f2bf(float f) {
    union { float f; unsigned u; } v; v.f = f;
    unsigned r = v.u + 0x7FFF + ((v.u >> 16) & 1);
    return (unsigned short)(r >> 16);
}
__device__ __forceinline__ float bf2f(unsigned short h) {
    union { unsigned u; float f; } v; v.u = ((unsigned)h) << 16;
    return v.f;
}
__device__ __forceinline__ unsigned pack_bf16rn(float lo, float hi) {
    unsigned ulo = __float_as_uint(lo) + 0x8000u;
    unsigned uhi = __float_as_uint(hi) + 0x8000u;
    return __builtin_amdgcn_perm(uhi, ulo, 0x07060302u);
}

#define SCq (0.125f * 1.44269504f)     // 1/sqrt(D) * log2(e) folded into qs
#define INV_SC (1.0f / (0.125f * 1.44269504f))

// ---------------- Kernel 0: weight prep -> B-frag layout bf16 ----------------
__global__ __launch_bounds__(256) void wprep_kernel(
    const float* __restrict__ Wq, const float* __restrict__ Wk,
    const float* __restrict__ Wv, unsigned short* __restrict__ wfrag)
{
    int t = blockIdx.x * 256 + threadIdx.x;   // 0..1023 = (dt,ksi,lane)
    int lane = t & 63, ksi = (t >> 6) & 3, dt = t >> 8;
    int l16 = lane & 15, quad = lane >> 4;
    int d = dt * 16 + l16;
    int c0 = ksi * 32 + quad * 8;
    short8 h8, l8, k8, v8;
    #pragma unroll
    for (int j = 0; j < 8; j++) {
        float w = Wq[(c0 + j) * Dsz + d];
        unsigned short h = f2bf(w);
        h8[j] = (short)h;
        l8[j] = (short)f2bf(w - bf2f(h));
        k8[j] = (short)f2bf(Wk[(c0 + j) * Dsz + d]);
        v8[j] = (short)f2bf(Wv[(c0 + j) * Dsz + d]);
    }
    int idx = (dt * 4 + ksi) * 64 + lane;
    ((short8*)wfrag)[0 * 1024 + idx] = h8;
    ((short8*)wfrag)[1 * 1024 + idx] = l8;
    ((short8*)wfrag)[2 * 1024 + idx] = k8;
    ((short8*)wfrag)[3 * 1024 + idx] = v8;
}

// ---------------- Kernel A: QKV projection via MFMA ----------------
// grid 1024 x 256; block = 64 rows; wave = d-tile dt. All global stores are
// coalesced b128 via an LDS transpose pass (reuses x-staging buffer).
__global__ __launch_bounds__(256) void qkv_kernel(
    const float* __restrict__ x, const unsigned short* __restrict__ wfrag,
    const float* __restrict__ bq, const float* __restrict__ bk,
    const float* __restrict__ bv,
    unsigned short* __restrict__ qs, unsigned short* __restrict__ ks2,
    unsigned short* __restrict__ vt2)
{
    __shared__ short lds[16384];          // 32 KB: xh|xl, then stq|stk|stv
    short* xh = lds;
    short* xl = lds + 8192;
    const int t    = threadIdx.x;
    const int lane = t & 63;
    const int l16  = lane & 15, quad = lane >> 4;
    const int dt   = t >> 6;
    const long rowbase = (long)blockIdx.x * 64;
    const int d = dt * 16 + l16;

    // weight B-frags: 16 coalesced b128 loads (L2-hot wfrag)
    short8 wqh[4], wql[4], wkf[4], wvf[4];
    #pragma unroll
    for (int ksi = 0; ksi < 4; ksi++) {
        int idx = (dt * 4 + ksi) * 64 + lane;
        wqh[ksi] = ((const short8*)wfrag)[0 * 1024 + idx];
        wql[ksi] = ((const short8*)wfrag)[1 * 1024 + idx];
        wkf[ksi] = ((const short8*)wfrag)[2 * 1024 + idx];
        wvf[ksi] = ((const short8*)wfrag)[3 * 1024 + idx];
    }

    // stage x -> bf16 hi/lo in A-frag layout
    {
        const int row = t & 63;
        const float* xrow = x + (rowbase + row) * Csz;
        #pragma unroll
        for (int p = 0; p < 4; p++) {
            int cb = (t >> 6) + p * 4;
            float4 a = *(const float4*)(xrow + cb * 8);
            float4 bb = *(const float4*)(xrow + cb * 8 + 4);
            float f[8] = {a.x, a.y, a.z, a.w, bb.x, bb.y, bb.z, bb.w};
            short8 hi, lo;
            #pragma unroll
            for (int i = 0; i < 8; i++) {
                unsigned short h = f2bf(f[i]);
                hi[i] = (short)h;
                lo[i] = (short)f2bf(f[i] - bf2f(h));
            }
            int unit = ((row >> 4) * 4 + (cb >> 2)) * 64 + ((row & 15) | ((cb & 3) << 4));
            *(short8*)&xh[unit * 8] = hi;
            *(short8*)&xl[unit * 8] = lo;
        }
    }
    __syncthreads();

    f32x4 aq[4], ak[4], av[4];
    #pragma unroll
    for (int i = 0; i < 4; i++) {
        aq[i] = (f32x4){0.f, 0.f, 0.f, 0.f};
        ak[i] = (f32x4){0.f, 0.f, 0.f, 0.f};
        av[i] = (f32x4){0.f, 0.f, 0.f, 0.f};
    }
    #pragma unroll
    for (int ksi = 0; ksi < 4; ksi++) {
        #pragma unroll
        for (int rt = 0; rt < 4; rt++) {
            short8 ah = *(const short8*)&xh[((rt * 4 + ksi) * 64 + lane) * 8];
            short8 al = *(const short8*)&xl[((rt * 4 + ksi) * 64 + lane) * 8];
            aq[rt] = __builtin_amdgcn_mfma_f32_16x16x32_bf16(ah, wqh[ksi], aq[rt], 0, 0, 0);
            aq[rt] = __builtin_amdgcn_mfma_f32_16x16x32_bf16(al, wqh[ksi], aq[rt], 0, 0, 0);
            aq[rt] = __builtin_amdgcn_mfma_f32_16x16x32_bf16(ah, wql[ksi], aq[rt], 0, 0, 0);
            ak[rt] = __builtin_amdgcn_mfma_f32_16x16x32_bf16(ah, wkf[ksi], ak[rt], 0, 0, 0);
            av[rt] = __builtin_amdgcn_mfma_f32_16x16x32_bf16(ah, wvf[ksi], av[rt], 0, 0, 0);
        }
    }

    // ---- epilogue: bias+relu -> LDS transpose -> coalesced b128 stores ----
    const float bqd = bq[d], bkd = bk[d], bvd = bv[d];
    const long b  = rowbase >> 10;
    const int  kt = (int)((rowbase >> 6) & 15);

    __syncthreads();                      // xh/xl reads all done; reuse buffer
    short* stq = lds;                     // [64][72]  q bf16 (scaled)
    short* stk = lds + 4608;              // [64][72]  k bf16
    short* stv = lds + 9216;              // [512][8]  V frag image

    float vv[4][4];   // [r][rt]
    #pragma unroll
    for (int rt = 0; rt < 4; rt++) {
        #pragma unroll
        for (int r = 0; r < 4; r++) {
            int nl = rt * 16 + quad * 4 + r;
            float q = fmaxf(aq[rt][r] + bqd, 0.f);
            float k = fmaxf(ak[rt][r] + bkd, 0.f);
            vv[r][rt] = fmaxf(av[rt][r] + bvd, 0.f);
            stq[nl * 72 + d] = (short)f2bf(q * SCq);
            stk[nl * 72 + d] = (short)f2bf(k);
        }
    }
    // V frag image writes: pi(n)=16*quad+4*r+rt -> slot=(dt*2+ck)*64+rho*16+l16
    #pragma unroll
    for (int r = 0; r < 4; r++) {
        int slot = (dt * 2 + (quad >> 1)) * 64 + (((quad & 1) << 1) | (r >> 1)) * 16 + l16;
        uint2 pk = make_uint2(pack_bf16rn(vv[r][0], vv[r][1]),
                              pack_bf16rn(vv[r][2], vv[r][3]));
        *(uint2*)&stv[slot * 8 + (r & 1) * 4] = pk;
    }
    __syncthreads();

    const long tbase = (long)(b * 16 + kt) * 512;
    #pragma unroll
    for (int i = 0; i < 2; i++) {
        int sidx = i * 256 + t;
        // qs [n][d]: fully coalesced
        int row = sidx >> 3, g = sidx & 7;
        short8 vq = *(const short8*)&stq[row * 72 + g * 8];
        ((short8*)qs)[(rowbase + row) * 8 + g] = vq;
        // K frag-major
        int kb = sidx >> 7, rem = sidx & 127, half = rem >> 6, lam = rem & 63;
        short8 vk = *(const short8*)&stk[(kb * 16 + (lam & 15)) * 72 + half * 32 + (lam >> 4) * 8];
        ((short8*)ks2)[tbase + kb * 128 + half * 64 + lam] = vk;
        // V frag-major (already in frag image order)
        short8 v8 = *(const short8*)&stv[sidx * 8];
        ((short8*)vt2)[tbase + sidx] = v8;
    }
}

// ---------------- Kernel B: barrier-free flash attention, 64 q/wave ----------------
// grid 512 x 128 thr (2 waves): b = blk&63 (XCD-affine: 64%8==0), qo = blk>>6.
__global__ __launch_bounds__(128) void attn_kernel(
    const unsigned short* __restrict__ qs,
    const unsigned short* __restrict__ ks2,
    const unsigned short* __restrict__ vt2,
    float* __restrict__ out)
{
    __shared__ short Pl[2][64][72];    // per-wave P round-trip + epilogue reuse

    const int t    = threadIdx.x;
    const int wave = t >> 6;
    const int lane = t & 63;
    const int l16  = lane & 15;
    const int quad = lane >> 4;
    const int b    = blockIdx.x & 63;
    const int qo   = blockIdx.x >> 6;
    const int qbase = qo * 128 + wave * 64;

    const short8* ks8 = (const short8*)ks2 + (long)b * 8192;
    const short8* vt8 = (const short8*)vt2 + (long)b * 8192;

    // Q A-frags: 4 strips of 16 rows
    short8 aq[4][2];
    #pragma unroll
    for (int s = 0; s < 4; s++) {
        const unsigned short* qp = qs + ((long)b * Nsz + qbase + s * 16 + l16) * Dsz + quad * 8;
        aq[s][0] = *(const short8*)(qp);
        aq[s][1] = *(const short8*)(qp + 32);
    }

    f32x4 O[4][4];
    float lsum[4][4];
    #pragma unroll
    for (int s = 0; s < 4; s++)
        #pragma unroll
        for (int i = 0; i < 4; i++) { O[s][i] = (f32x4){0.f,0.f,0.f,0.f}; lsum[s][i] = 0.f; }

    // K-frag ping-pong buffers (no mov copies)
    short8 kf[2][4][2];
    #pragma unroll
    for (int kb = 0; kb < 4; kb++) {
        kf[0][kb][0] = ks8[(kb * 2 + 0) * 64 + lane];
        kf[0][kb][1] = ks8[(kb * 2 + 1) * 64 + lane];
    }

    for (int kt = 0; kt < 16; kt++) {
        const int cur = kt & 1;
        // V frags half 0 early
        short8 bvf0[4];
        #pragma unroll
        for (int cb = 0; cb < 4; cb++)
            bvf0[cb] = vt8[((long)kt * 8 + cb * 2 + 0) * 64 + lane];

        // ---- group 0: strips 0,1 ----
        f32x4 sc[2][4];
        #pragma unroll
        for (int s = 0; s < 2; s++) {
            #pragma unroll
            for (int kb = 0; kb < 4; kb++) {
                f32x4 z = (f32x4){0.f, 0.f, 0.f, 0.f};
                z = __builtin_amdgcn_mfma_f32_16x16x32_bf16(aq[s][0], kf[cur][kb][0], z, 0, 0, 0);
                z = __builtin_amdgcn_mfma_f32_16x16x32_bf16(aq[s][1], kf[cur][kb][1], z, 0, 0, 0);
                sc[s][kb] = z;
            }
        }
        // prefetch next kt's K-frags into other buffer (flies under exp+PV)
        {
            int ktn = (kt + 1) & 15;
            #pragma unroll
            for (int kb = 0; kb < 4; kb++) {
                kf[1 - cur][kb][0] = ks8[((long)ktn * 8 + kb * 2 + 0) * 64 + lane];
                kf[1 - cur][kb][1] = ks8[((long)ktn * 8 + kb * 2 + 1) * 64 + lane];
            }
        }
        #pragma unroll
        for (int s = 0; s < 2; s++) {
            #pragma unroll
            for (int r = 0; r < 4; r++) {
                float p0 = __builtin_amdgcn_exp2f(sc[s][0][r]);
                float p1 = __builtin_amdgcn_exp2f(sc[s][1][r]);
                float p2 = __builtin_amdgcn_exp2f(sc[s][2][r]);
                float p3 = __builtin_amdgcn_exp2f(sc[s][3][r]);
                lsum[s][r] += (p0 + p1) + (p2 + p3);
                *(uint2*)&Pl[wave][s * 16 + quad * 4 + r][l16 * 4] =
                    make_uint2(pack_bf16rn(p0, p1), pack_bf16rn(p2, p3));
            }
        }
        // ---- group 1: strips 2,3 ----
        #pragma unroll
        for (int s = 0; s < 2; s++) {
            #pragma unroll
            for (int kb = 0; kb < 4; kb++) {
                f32x4 z = (f32x4){0.f, 0.f, 0.f, 0.f};
                z = __builtin_amdgcn_mfma_f32_16x16x32_bf16(aq[s + 2][0], kf[cur][kb][0], z, 0, 0, 0);
                z = __builtin_amdgcn_mfma_f32_16x16x32_bf16(aq[s + 2][1], kf[cur][kb][1], z, 0, 0, 0);
                sc[s][kb] = z;
            }
        }
        #pragma unroll
        for (int s = 0; s < 2; s++) {
            #pragma unroll
            for (int r = 0; r < 4; r++) {
                float p0 = __builtin_amdgcn_exp2f(sc[s][0][r]);
                float p1 = __builtin_amdgcn_exp2f(sc[s][1][r]);
                float p2 = __builtin_amdgcn_exp2f(sc[s][2][r]);
                float p3 = __builtin_amdgcn_exp2f(sc[s][3][r]);
                lsum[s + 2][r] += (p0 + p1) + (p2 + p3);
                *(uint2*)&Pl[wave][(s + 2) * 16 + quad * 4 + r][l16 * 4] =
                    make_uint2(pack_bf16rn(p0, p1), pack_bf16rn(p2, p3));
            }
        }
        // V frags half 1 (short lifetime)
        short8 bvf1[4];
        #pragma unroll
        for (int cb = 0; cb < 4; cb++)
            bvf1[cb] = vt8[((long)kt * 8 + cb * 2 + 1) * 64 + lane];

        // ---- PV: all strips ----
        #pragma unroll
        for (int s = 0; s < 4; s++) {
            short8 ap0 = *(const short8*)&Pl[wave][s * 16 + l16][0 * 32 + quad * 8];
            #pragma unroll
            for (int cb = 0; cb < 4; cb++)
                O[s][cb] = __builtin_amdgcn_mfma_f32_16x16x32_bf16(ap0, bvf0[cb], O[s][cb], 0, 0, 0);
            short8 ap1 = *(const short8*)&Pl[wave][s * 16 + l16][1 * 32 + quad * 8];
            #pragma unroll
            for (int cb = 0; cb < 4; cb++)
                O[s][cb] = __builtin_amdgcn_mfma_f32_16x16x32_bf16(ap1, bvf1[cb], O[s][cb], 0, 0, 0);
        }
    }

    // deferred row-sum reduction
    #pragma unroll
    for (int s = 0; s < 4; s++)
        #pragma unroll
        for (int r = 0; r < 4; r++)
            #pragma unroll
            for (int off = 1; off < 16; off <<= 1)
                lsum[s][r] += __shfl_xor(lsum[s][r], off);

    // epilogue: per strip, LDS f32 transpose -> coalesced f32x4 stores (+q)
    float* fst = (float*)&Pl[wave][0][0];    // 9216 B/wave >= 16*68*4
    #pragma unroll
    for (int s = 0; s < 4; s++) {
        #pragma unroll
        for (int r = 0; r < 4; r++) {
            float rl = 1.0f / lsum[s][r];
            #pragma unroll
            for (int cb = 0; cb < 4; cb++)
                fst[(quad * 4 + r) * 68 + cb * 16 + l16] = O[s][cb][r] * rl;
        }
        #pragma unroll
        for (int j = 0; j < 4; j++) {
            int vidx = j * 64 + lane;
            int row = vidx >> 4, dp = (vidx & 15) * 4;
            f32x4 ov = *(const f32x4*)&fst[row * 68 + dp];
            long nrow = (long)b * Nsz + qbase + s * 16 + row;
            uint2 qv = *(const uint2*)(qs + nrow * Dsz + dp);
            ov[0] += bf2f((unsigned short)(qv.x)) * INV_SC;
            ov[1] += bf2f((unsigned short)(qv.x >> 16)) * INV_SC;
            ov[2] += bf2f((unsigned short)(qv.y)) * INV_SC;
            ov[3] += bf2f((unsigned short)(qv.y >> 16)) * INV_SC;
            *(f32x4*)(out + nrow * Dsz + dp) = ov;
        }
    }
}

extern "C" void kernel_launch(void* const* d_in, const int* in_sizes, int n_in,
                              void* d_out, int out_size, void* d_ws, size_t ws_size,
                              hipStream_t stream) {
    const float* x  = (const float*)d_in[0];
    const float* Wq = (const float*)d_in[1];
    const float* bq = (const float*)d_in[2];
    const float* Wk = (const float*)d_in[3];
    const float* bk = (const float*)d_in[4];
    const float* Wv = (const float*)d_in[5];
    const float* bv = (const float*)d_in[6];
    float* out = (float*)d_out;

    char* ws = (char*)d_ws;
    unsigned short* qsc   = (unsigned short*)ws;                 // 8 MB bf16 q*SC, [n][d]
    unsigned short* ks2   = (unsigned short*)(ws + 0x1000000);   // 8 MB bf16 K frag-major
    unsigned short* vt2   = (unsigned short*)(ws + 0x2000000);   // 8 MB bf16 V frag-major
    unsigned short* wfrag = (unsigned short*)(ws + 0x3000000);   // 64 KB W frags

    wprep_kernel<<<dim3(4), dim3(256), 0, stream>>>(Wq, Wk, Wv, wfrag);
    qkv_kernel<<<dim3(1024), dim3(256), 0, stream>>>(
        x, wfrag, bq, bk, bv, qsc, ks2, vt2);
    attn_kernel<<<dim3(512), dim3(128), 0, stream>>>(
        qsc, ks2, vt2, out);
}

// Round 7
// 126.955 us; speedup vs baseline: 1.3192x; 1.3192x over previous
//
#include <hip/hip_runtime.h>
#include <hip/hip_bf16.h>

// SelfAttentionLayer: B=64, N=1024, C=128, D=64
// R6: attn reverted to R4's proven 32-q/wave barrier-free structure.
// R5's regression root-cause: runtime-indexed register array (kf[cur]) ->
// scratch spills (100 MB attn WRITE_SIZE). Fixed via compile-time kfA/kfB
// alternation (kt-loop body x2). Epilogue vectorized through LDS. qkv kept
// from R5 (all-coalesced b128 stores via LDS transpose).

#define Bsz 64
#define Nsz 1024
#define Csz 128
#define Dsz 64

typedef __attribute__((ext_vector_type(8))) short short8;
typedef __attribute__((ext_vector_type(4))) float f32x4;

__device__ __forceinline__ unsigned short f2bf(float f) {
    union { float f; unsigned u; } v; v.f = f;
    unsigned r = v.u + 0x7FFF + ((v.u >> 16) & 1);
    return (unsigned short)(r >> 16);
}
__device__ __forceinline__ float bf2f(unsigned short h) {
    union { unsigned u; float f; } v; v.u = ((unsigned)h) << 16;
    return v.f;
}
__device__ __forceinline__ unsigned pack_bf16rn(float lo, float hi) {
    unsigned ulo = __float_as_uint(lo) + 0x8000u;
    unsigned uhi = __float_as_uint(hi) + 0x8000u;
    return __builtin_amdgcn_perm(uhi, ulo, 0x07060302u);
}

#define SCq (0.125f * 1.44269504f)     // 1/sqrt(D) * log2(e) folded into qs
#define INV_SC (1.0f / (0.125f * 1.44269504f))

// ---------------- Kernel 0: weight prep -> B-frag layout bf16 ----------------
__global__ __launch_bounds__(256) void wprep_kernel(
    const float* __restrict__ Wq, const float* __restrict__ Wk,
    const float* __restrict__ Wv, unsigned short* __restrict__ wfrag)
{
    int t = blockIdx.x * 256 + threadIdx.x;   // 0..1023 = (dt,ksi,lane)
    int lane = t & 63, ksi = (t >> 6) & 3, dt = t >> 8;
    int l16 = lane & 15, quad = lane >> 4;
    int d = dt * 16 + l16;
    int c0 = ksi * 32 + quad * 8;
    short8 h8, l8, k8, v8;
    #pragma unroll
    for (int j = 0; j < 8; j++) {
        float w = Wq[(c0 + j) * Dsz + d];
        unsigned short h = f2bf(w);
        h8[j] = (short)h;
        l8[j] = (short)f2bf(w - bf2f(h));
        k8[j] = (short)f2bf(Wk[(c0 + j) * Dsz + d]);
        v8[j] = (short)f2bf(Wv[(c0 + j) * Dsz + d]);
    }
    int idx = (dt * 4 + ksi) * 64 + lane;
    ((short8*)wfrag)[0 * 1024 + idx] = h8;
    ((short8*)wfrag)[1 * 1024 + idx] = l8;
    ((short8*)wfrag)[2 * 1024 + idx] = k8;
    ((short8*)wfrag)[3 * 1024 + idx] = v8;
}

// ---------------- Kernel A: QKV projection via MFMA (R5) ----------------
__global__ __launch_bounds__(256) void qkv_kernel(
    const float* __restrict__ x, const unsigned short* __restrict__ wfrag,
    const float* __restrict__ bq, const float* __restrict__ bk,
    const float* __restrict__ bv,
    unsigned short* __restrict__ qs, unsigned short* __restrict__ ks2,
    unsigned short* __restrict__ vt2)
{
    __shared__ short lds[16384];          // 32 KB: xh|xl, then stq|stk|stv
    short* xh = lds;
    short* xl = lds + 8192;
    const int t    = threadIdx.x;
    const int lane = t & 63;
    const int l16  = lane & 15, quad = lane >> 4;
    const int dt   = t >> 6;
    const long rowbase = (long)blockIdx.x * 64;
    const int d = dt * 16 + l16;

    short8 wqh[4], wql[4], wkf[4], wvf[4];
    #pragma unroll
    for (int ksi = 0; ksi < 4; ksi++) {
        int idx = (dt * 4 + ksi) * 64 + lane;
        wqh[ksi] = ((const short8*)wfrag)[0 * 1024 + idx];
        wql[ksi] = ((const short8*)wfrag)[1 * 1024 + idx];
        wkf[ksi] = ((const short8*)wfrag)[2 * 1024 + idx];
        wvf[ksi] = ((const short8*)wfrag)[3 * 1024 + idx];
    }

    {
        const int row = t & 63;
        const float* xrow = x + (rowbase + row) * Csz;
        #pragma unroll
        for (int p = 0; p < 4; p++) {
            int cb = (t >> 6) + p * 4;
            float4 a = *(const float4*)(xrow + cb * 8);
            float4 bb = *(const float4*)(xrow + cb * 8 + 4);
            float f[8] = {a.x, a.y, a.z, a.w, bb.x, bb.y, bb.z, bb.w};
            short8 hi, lo;
            #pragma unroll
            for (int i = 0; i < 8; i++) {
                unsigned short h = f2bf(f[i]);
                hi[i] = (short)h;
                lo[i] = (short)f2bf(f[i] - bf2f(h));
            }
            int unit = ((row >> 4) * 4 + (cb >> 2)) * 64 + ((row & 15) | ((cb & 3) << 4));
            *(short8*)&xh[unit * 8] = hi;
            *(short8*)&xl[unit * 8] = lo;
        }
    }
    __syncthreads();

    f32x4 aq[4], ak[4], av[4];
    #pragma unroll
    for (int i = 0; i < 4; i++) {
        aq[i] = (f32x4){0.f, 0.f, 0.f, 0.f};
        ak[i] = (f32x4){0.f, 0.f, 0.f, 0.f};
        av[i] = (f32x4){0.f, 0.f, 0.f, 0.f};
    }
    #pragma unroll
    for (int ksi = 0; ksi < 4; ksi++) {
        #pragma unroll
        for (int rt = 0; rt < 4; rt++) {
            short8 ah = *(const short8*)&xh[((rt * 4 + ksi) * 64 + lane) * 8];
            short8 al = *(const short8*)&xl[((rt * 4 + ksi) * 64 + lane) * 8];
            aq[rt] = __builtin_amdgcn_mfma_f32_16x16x32_bf16(ah, wqh[ksi], aq[rt], 0, 0, 0);
            aq[rt] = __builtin_amdgcn_mfma_f32_16x16x32_bf16(al, wqh[ksi], aq[rt], 0, 0, 0);
            aq[rt] = __builtin_amdgcn_mfma_f32_16x16x32_bf16(ah, wql[ksi], aq[rt], 0, 0, 0);
            ak[rt] = __builtin_amdgcn_mfma_f32_16x16x32_bf16(ah, wkf[ksi], ak[rt], 0, 0, 0);
            av[rt] = __builtin_amdgcn_mfma_f32_16x16x32_bf16(ah, wvf[ksi], av[rt], 0, 0, 0);
        }
    }

    const float bqd = bq[d], bkd = bk[d], bvd = bv[d];
    const long b  = rowbase >> 10;
    const int  kt = (int)((rowbase >> 6) & 15);

    __syncthreads();
    short* stq = lds;                     // [64][72]
    short* stk = lds + 4608;              // [64][72]
    short* stv = lds + 9216;              // [512][8]

    float vv[4][4];
    #pragma unroll
    for (int rt = 0; rt < 4; rt++) {
        #pragma unroll
        for (int r = 0; r < 4; r++) {
            int nl = rt * 16 + quad * 4 + r;
            float q = fmaxf(aq[rt][r] + bqd, 0.f);
            float k = fmaxf(ak[rt][r] + bkd, 0.f);
            vv[r][rt] = fmaxf(av[rt][r] + bvd, 0.f);
            stq[nl * 72 + d] = (short)f2bf(q * SCq);
            stk[nl * 72 + d] = (short)f2bf(k);
        }
    }
    #pragma unroll
    for (int r = 0; r < 4; r++) {
        int slot = (dt * 2 + (quad >> 1)) * 64 + (((quad & 1) << 1) | (r >> 1)) * 16 + l16;
        uint2 pk = make_uint2(pack_bf16rn(vv[r][0], vv[r][1]),
                              pack_bf16rn(vv[r][2], vv[r][3]));
        *(uint2*)&stv[slot * 8 + (r & 1) * 4] = pk;
    }
    __syncthreads();

    const long tbase = (long)(b * 16 + kt) * 512;
    #pragma unroll
    for (int i = 0; i < 2; i++) {
        int sidx = i * 256 + t;
        int row = sidx >> 3, g = sidx & 7;
        short8 vq = *(const short8*)&stq[row * 72 + g * 8];
        ((short8*)qs)[(rowbase + row) * 8 + g] = vq;
        int kb = sidx >> 7, rem = sidx & 127, half = rem >> 6, lam = rem & 63;
        short8 vk = *(const short8*)&stk[(kb * 16 + (lam & 15)) * 72 + half * 32 + (lam >> 4) * 8];
        ((short8*)ks2)[tbase + kb * 128 + half * 64 + lam] = vk;
        short8 v8 = *(const short8*)&stv[sidx * 8];
        ((short8*)vt2)[tbase + sidx] = v8;
    }
}

// ---------------- Kernel B: barrier-free flash attention (R4 + fixes) ----------------
// grid 512 x 256: b = blk&63 (XCD affinity), qh = blk>>6. 4 waves x 32 q.
__global__ __launch_bounds__(256) void attn_kernel(
    const unsigned short* __restrict__ qs,
    const unsigned short* __restrict__ ks2,
    const unsigned short* __restrict__ vt2,
    float* __restrict__ out)
{
    __shared__ short Pl[4][32][72];    // per-wave P round-trip + epilogue reuse

    const int t    = threadIdx.x;
    const int wave = t >> 6;
    const int lane = t & 63;
    const int l16  = lane & 15;
    const int quad = lane >> 4;
    const int b    = blockIdx.x & 63;
    const int qh   = blockIdx.x >> 6;
    const int qbase = qh * 128 + wave * 32;

    const short8* ks8 = (const short8*)ks2 + (long)b * 8192;
    const short8* vt8 = (const short8*)vt2 + (long)b * 8192;

    short8 aq[2][2];
    #pragma unroll
    for (int s = 0; s < 2; s++) {
        const unsigned short* qp = qs + ((long)b * Nsz + qbase + s * 16 + l16) * Dsz + quad * 8;
        aq[s][0] = *(const short8*)(qp);
        aq[s][1] = *(const short8*)(qp + 32);
    }

    f32x4 O[2][4];
    float lsum[2][4];
    #pragma unroll
    for (int s = 0; s < 2; s++)
        #pragma unroll
        for (int i = 0; i < 4; i++) { O[s][i] = (f32x4){0.f,0.f,0.f,0.f}; lsum[s][i] = 0.f; }

    short8 kfA[4][2], kfB[4][2];
    #pragma unroll
    for (int kb = 0; kb < 4; kb++) {
        kfA[kb][0] = ks8[(kb * 2 + 0) * 64 + lane];
        kfA[kb][1] = ks8[(kb * 2 + 1) * 64 + lane];
    }

    // one kt step: compute with `cur`, prefetch kt+1 into `nxt` (compile-time roles)
    auto step = [&](int kt, short8 (&cur)[4][2], short8 (&nxt)[4][2]) {
        short8 bvf[2][4];
        #pragma unroll
        for (int cb = 0; cb < 4; cb++) {
            bvf[0][cb] = vt8[((long)kt * 8 + cb * 2 + 0) * 64 + lane];
            bvf[1][cb] = vt8[((long)kt * 8 + cb * 2 + 1) * 64 + lane];
        }

        f32x4 sc[2][4];
        #pragma unroll
        for (int s = 0; s < 2; s++) {
            #pragma unroll
            for (int kb = 0; kb < 4; kb++) {
                f32x4 z = (f32x4){0.f, 0.f, 0.f, 0.f};
                z = __builtin_amdgcn_mfma_f32_16x16x32_bf16(aq[s][0], cur[kb][0], z, 0, 0, 0);
                z = __builtin_amdgcn_mfma_f32_16x16x32_bf16(aq[s][1], cur[kb][1], z, 0, 0, 0);
                sc[s][kb] = z;
            }
        }

        {
            int ktn = (kt + 1) & 15;
            #pragma unroll
            for (int kb = 0; kb < 4; kb++) {
                nxt[kb][0] = ks8[((long)ktn * 8 + kb * 2 + 0) * 64 + lane];
                nxt[kb][1] = ks8[((long)ktn * 8 + kb * 2 + 1) * 64 + lane];
            }
        }

        #pragma unroll
        for (int s = 0; s < 2; s++) {
            #pragma unroll
            for (int r = 0; r < 4; r++) {
                float p0 = __builtin_amdgcn_exp2f(sc[s][0][r]);
                float p1 = __builtin_amdgcn_exp2f(sc[s][1][r]);
                float p2 = __builtin_amdgcn_exp2f(sc[s][2][r]);
                float p3 = __builtin_amdgcn_exp2f(sc[s][3][r]);
                lsum[s][r] += (p0 + p1) + (p2 + p3);
                *(uint2*)&Pl[wave][s * 16 + quad * 4 + r][l16 * 4] =
                    make_uint2(pack_bf16rn(p0, p1), pack_bf16rn(p2, p3));
            }
        }

        #pragma unroll
        for (int ck = 0; ck < 2; ck++) {
            #pragma unroll
            for (int s = 0; s < 2; s++) {
                short8 ap = *(const short8*)&Pl[wave][s * 16 + l16][ck * 32 + quad * 8];
                #pragma unroll
                for (int cb = 0; cb < 4; cb++) {
                    O[s][cb] = __builtin_amdgcn_mfma_f32_16x16x32_bf16(ap, bvf[ck][cb], O[s][cb], 0, 0, 0);
                }
            }
        }
    };

    for (int kt = 0; kt < 16; kt += 2) {
        step(kt,     kfA, kfB);
        step(kt + 1, kfB, kfA);
    }

    #pragma unroll
    for (int s = 0; s < 2; s++)
        #pragma unroll
        for (int r = 0; r < 4; r++)
            #pragma unroll
            for (int off = 1; off < 16; off <<= 1)
                lsum[s][r] += __shfl_xor(lsum[s][r], off);

    // epilogue: per-strip f32 transpose via this wave's Pl slab -> vec stores
    float* fst = (float*)&Pl[wave][0][0];    // 4608 B >= 16*68*4 = 4352
    #pragma unroll
    for (int s = 0; s < 2; s++) {
        #pragma unroll
        for (int r = 0; r < 4; r++) {
            float rl = 1.0f / lsum[s][r];
            #pragma unroll
            for (int cb = 0; cb < 4; cb++)
                fst[(quad * 4 + r) * 68 + cb * 16 + l16] = O[s][cb][r] * rl;
        }
        #pragma unroll
        for (int j = 0; j < 4; j++) {
            int vidx = j * 64 + lane;
            int row = vidx >> 4, dp = (vidx & 15) * 4;
            f32x4 ov = *(const f32x4*)&fst[row * 68 + dp];
            long nrow = (long)b * Nsz + qbase + s * 16 + row;
            uint2 qv = *(const uint2*)(qs + nrow * Dsz + dp);
            ov[0] += bf2f((unsigned short)(qv.x)) * INV_SC;
            ov[1] += bf2f((unsigned short)(qv.x >> 16)) * INV_SC;
            ov[2] += bf2f((unsigned short)(qv.y)) * INV_SC;
            ov[3] += bf2f((unsigned short)(qv.y >> 16)) * INV_SC;
            *(f32x4*)(out + nrow * Dsz + dp) = ov;
        }
    }
}

extern "C" void kernel_launch(void* const* d_in, const int* in_sizes, int n_in,
                              void* d_out, int out_size, void* d_ws, size_t ws_size,
                              hipStream_t stream) {
    const float* x  = (const float*)d_in[0];
    const float* Wq = (const float*)d_in[1];
    const float* bq = (const float*)d_in[2];
    const float* Wk = (const float*)d_in[3];
    const float* bk = (const float*)d_in[4];
    const float* Wv = (const float*)d_in[5];
    const float* bv = (const float*)d_in[6];
    float* out = (float*)d_out;

    char* ws = (char*)d_ws;
    unsigned short* qsc   = (unsigned short*)ws;                 // 8 MB bf16 q*SC, [n][d]
    unsigned short* ks2   = (unsigned short*)(ws + 0x1000000);   // 8 MB bf16 K frag-major
    unsigned short* vt2   = (unsigned short*)(ws + 0x2000000);   // 8 MB bf16 V frag-major
    unsigned short* wfrag = (unsigned short*)(ws + 0x3000000);   // 64 KB W frags

    wprep_kernel<<<dim3(4), dim3(256), 0, stream>>>(Wq, Wk, Wv, wfrag);
    qkv_kernel<<<dim3(1024), dim3(256), 0, stream>>>(
        x, wfrag, bq, bk, bv, qsc, ks2, vt2);
    attn_kernel<<<dim3(512), dim3(256), 0, stream>>>(
        qsc, ks2, vt2, out);
}

// Round 8
// 124.467 us; speedup vs baseline: 1.3455x; 1.0200x over previous
//
#include <hip/hip_runtime.h>
#include <hip/hip_bf16.h>

// SelfAttentionLayer: B=64, N=1024, C=128, D=64
// R7: qkv drops the q hi/lo split-bf16 path entirely — the +q output term is
// reconstructed from the bf16 qs copy anyway, so split precision was wasted
// (absmax 0.031 == bf16 rounding of q). Single bf16 MFMA for q/k/v: removes
// xl staging, wql frags, 32/80 MFMAs, ~40% of conversion VALU. attn = R6
// (barrier-free, frag-major, compile-time ping-pong, no spills).

#define Bsz 64
#define Nsz 1024
#define Csz 128
#define Dsz 64

typedef __attribute__((ext_vector_type(8))) short short8;
typedef __attribute__((ext_vector_type(4))) float f32x4;

__device__ __forceinline__ unsigned short f2bf(float f) {
    union { float f; unsigned u; } v; v.f = f;
    unsigned r = v.u + 0x7FFF + ((v.u >> 16) & 1);
    return (unsigned short)(r >> 16);
}
__device__ __forceinline__ float bf2f(unsigned short h) {
    union { unsigned u; float f; } v; v.u = ((unsigned)h) << 16;
    return v.f;
}
// pack two fp32 -> bf16x2 dword (round-nearest, ties-up): 3 VALU ops
__device__ __forceinline__ unsigned pack_bf16rn(float lo, float hi) {
    unsigned ulo = __float_as_uint(lo) + 0x8000u;
    unsigned uhi = __float_as_uint(hi) + 0x8000u;
    return __builtin_amdgcn_perm(uhi, ulo, 0x07060302u);
}

#define SCq (0.125f * 1.44269504f)     // 1/sqrt(D) * log2(e) folded into qs
#define INV_SC (1.0f / (0.125f * 1.44269504f))

// ---------------- Kernel 0: weight prep -> B-frag layout bf16 ----------------
// wfrag: [mat:{q,k,v}][dt*4+ksi][lane][8] shorts (3 x 16 KB)
__global__ __launch_bounds__(256) void wprep_kernel(
    const float* __restrict__ Wq, const float* __restrict__ Wk,
    const float* __restrict__ Wv, unsigned short* __restrict__ wfrag)
{
    int t = blockIdx.x * 256 + threadIdx.x;   // 0..1023 = (dt,ksi,lane)
    int lane = t & 63, ksi = (t >> 6) & 3, dt = t >> 8;
    int l16 = lane & 15, quad = lane >> 4;
    int d = dt * 16 + l16;
    int c0 = ksi * 32 + quad * 8;
    short8 q8, k8, v8;
    #pragma unroll
    for (int j = 0; j < 8; j++) {
        q8[j] = (short)f2bf(Wq[(c0 + j) * Dsz + d]);
        k8[j] = (short)f2bf(Wk[(c0 + j) * Dsz + d]);
        v8[j] = (short)f2bf(Wv[(c0 + j) * Dsz + d]);
    }
    int idx = (dt * 4 + ksi) * 64 + lane;
    ((short8*)wfrag)[0 * 1024 + idx] = q8;
    ((short8*)wfrag)[1 * 1024 + idx] = k8;
    ((short8*)wfrag)[2 * 1024 + idx] = v8;
}

// ---------------- Kernel A: QKV projection via MFMA ----------------
// grid 1024 x 256; block = 64 rows; wave = d-tile dt. Single bf16 term per
// output. All global stores coalesced b128 via LDS transpose pass.
__global__ __launch_bounds__(256) void qkv_kernel(
    const float* __restrict__ x, const unsigned short* __restrict__ wfrag,
    const float* __restrict__ bq, const float* __restrict__ bk,
    const float* __restrict__ bv,
    unsigned short* __restrict__ qs, unsigned short* __restrict__ ks2,
    unsigned short* __restrict__ vt2)
{
    __shared__ short lds[16384];          // 32 KB: xh (16 KB) | transpose bufs
    short* xh = lds;
    const int t    = threadIdx.x;
    const int lane = t & 63;
    const int l16  = lane & 15, quad = lane >> 4;
    const int dt   = t >> 6;
    const long rowbase = (long)blockIdx.x * 64;
    const int d = dt * 16 + l16;

    // weight B-frags: 12 coalesced b128 loads (L2-hot wfrag)
    short8 wqf[4], wkf[4], wvf[4];
    #pragma unroll
    for (int ksi = 0; ksi < 4; ksi++) {
        int idx = (dt * 4 + ksi) * 64 + lane;
        wqf[ksi] = ((const short8*)wfrag)[0 * 1024 + idx];
        wkf[ksi] = ((const short8*)wfrag)[1 * 1024 + idx];
        wvf[ksi] = ((const short8*)wfrag)[2 * 1024 + idx];
    }

    // stage x -> bf16 in A-frag layout (4 v_perm packs per chunk)
    {
        const int row = t & 63;
        const float* xrow = x + (rowbase + row) * Csz;
        #pragma unroll
        for (int p = 0; p < 4; p++) {
            int cb = (t >> 6) + p * 4;
            float4 a  = *(const float4*)(xrow + cb * 8);
            float4 bb = *(const float4*)(xrow + cb * 8 + 4);
            uint4 hi4;
            hi4.x = pack_bf16rn(a.x,  a.y);
            hi4.y = pack_bf16rn(a.z,  a.w);
            hi4.z = pack_bf16rn(bb.x, bb.y);
            hi4.w = pack_bf16rn(bb.z, bb.w);
            int unit = ((row >> 4) * 4 + (cb >> 2)) * 64 + ((row & 15) | ((cb & 3) << 4));
            *(uint4*)&xh[unit * 8] = hi4;
        }
    }
    __syncthreads();

    f32x4 aq[4], ak[4], av[4];
    #pragma unroll
    for (int i = 0; i < 4; i++) {
        aq[i] = (f32x4){0.f, 0.f, 0.f, 0.f};
        ak[i] = (f32x4){0.f, 0.f, 0.f, 0.f};
        av[i] = (f32x4){0.f, 0.f, 0.f, 0.f};
    }
    #pragma unroll
    for (int ksi = 0; ksi < 4; ksi++) {
        #pragma unroll
        for (int rt = 0; rt < 4; rt++) {
            short8 ah = *(const short8*)&xh[((rt * 4 + ksi) * 64 + lane) * 8];
            aq[rt] = __builtin_amdgcn_mfma_f32_16x16x32_bf16(ah, wqf[ksi], aq[rt], 0, 0, 0);
            ak[rt] = __builtin_amdgcn_mfma_f32_16x16x32_bf16(ah, wkf[ksi], ak[rt], 0, 0, 0);
            av[rt] = __builtin_amdgcn_mfma_f32_16x16x32_bf16(ah, wvf[ksi], av[rt], 0, 0, 0);
        }
    }

    // ---- epilogue: bias+relu -> LDS transpose -> coalesced b128 stores ----
    const float bqd = bq[d], bkd = bk[d], bvd = bv[d];
    const long b  = rowbase >> 10;
    const int  kt = (int)((rowbase >> 6) & 15);

    __syncthreads();                      // xh reads all done; reuse buffer
    short* stq = lds;                     // [64][72]
    short* stk = lds + 4608;              // [64][72]
    short* stv = lds + 9216;              // [512][8]

    float vv[4][4];
    #pragma unroll
    for (int rt = 0; rt < 4; rt++) {
        #pragma unroll
        for (int r = 0; r < 4; r++) {
            int nl = rt * 16 + quad * 4 + r;
            float q = fmaxf(aq[rt][r] + bqd, 0.f);
            float k = fmaxf(ak[rt][r] + bkd, 0.f);
            vv[r][rt] = fmaxf(av[rt][r] + bvd, 0.f);
            stq[nl * 72 + d] = (short)f2bf(q * SCq);
            stk[nl * 72 + d] = (short)f2bf(k);
        }
    }
    #pragma unroll
    for (int r = 0; r < 4; r++) {
        int slot = (dt * 2 + (quad >> 1)) * 64 + (((quad & 1) << 1) | (r >> 1)) * 16 + l16;
        uint2 pk = make_uint2(pack_bf16rn(vv[r][0], vv[r][1]),
                              pack_bf16rn(vv[r][2], vv[r][3]));
        *(uint2*)&stv[slot * 8 + (r & 1) * 4] = pk;
    }
    __syncthreads();

    const long tbase = (long)(b * 16 + kt) * 512;
    #pragma unroll
    for (int i = 0; i < 2; i++) {
        int sidx = i * 256 + t;
        int row = sidx >> 3, g = sidx & 7;
        short8 vq = *(const short8*)&stq[row * 72 + g * 8];
        ((short8*)qs)[(rowbase + row) * 8 + g] = vq;
        int kb = sidx >> 7, rem = sidx & 127, half = rem >> 6, lam = rem & 63;
        short8 vk = *(const short8*)&stk[(kb * 16 + (lam & 15)) * 72 + half * 32 + (lam >> 4) * 8];
        ((short8*)ks2)[tbase + kb * 128 + half * 64 + lam] = vk;
        short8 v8 = *(const short8*)&stv[sidx * 8];
        ((short8*)vt2)[tbase + sidx] = v8;
    }
}

// ---------------- Kernel B: barrier-free flash attention (R6) ----------------
// grid 512 x 256: b = blk&63 (XCD affinity), qh = blk>>6. 4 waves x 32 q.
__global__ __launch_bounds__(256) void attn_kernel(
    const unsigned short* __restrict__ qs,
    const unsigned short* __restrict__ ks2,
    const unsigned short* __restrict__ vt2,
    float* __restrict__ out)
{
    __shared__ short Pl[4][32][72];    // per-wave P round-trip + epilogue reuse

    const int t    = threadIdx.x;
    const int wave = t >> 6;
    const int lane = t & 63;
    const int l16  = lane & 15;
    const int quad = lane >> 4;
    const int b    = blockIdx.x & 63;
    const int qh   = blockIdx.x >> 6;
    const int qbase = qh * 128 + wave * 32;

    const short8* ks8 = (const short8*)ks2 + (long)b * 8192;
    const short8* vt8 = (const short8*)vt2 + (long)b * 8192;

    short8 aq[2][2];
    #pragma unroll
    for (int s = 0; s < 2; s++) {
        const unsigned short* qp = qs + ((long)b * Nsz + qbase + s * 16 + l16) * Dsz + quad * 8;
        aq[s][0] = *(const short8*)(qp);
        aq[s][1] = *(const short8*)(qp + 32);
    }

    f32x4 O[2][4];
    float lsum[2][4];
    #pragma unroll
    for (int s = 0; s < 2; s++)
        #pragma unroll
        for (int i = 0; i < 4; i++) { O[s][i] = (f32x4){0.f,0.f,0.f,0.f}; lsum[s][i] = 0.f; }

    short8 kfA[4][2], kfB[4][2];
    #pragma unroll
    for (int kb = 0; kb < 4; kb++) {
        kfA[kb][0] = ks8[(kb * 2 + 0) * 64 + lane];
        kfA[kb][1] = ks8[(kb * 2 + 1) * 64 + lane];
    }

    auto step = [&](int kt, short8 (&cur)[4][2], short8 (&nxt)[4][2]) {
        short8 bvf[2][4];
        #pragma unroll
        for (int cb = 0; cb < 4; cb++) {
            bvf[0][cb] = vt8[((long)kt * 8 + cb * 2 + 0) * 64 + lane];
            bvf[1][cb] = vt8[((long)kt * 8 + cb * 2 + 1) * 64 + lane];
        }

        f32x4 sc[2][4];
        #pragma unroll
        for (int s = 0; s < 2; s++) {
            #pragma unroll
            for (int kb = 0; kb < 4; kb++) {
                f32x4 z = (f32x4){0.f, 0.f, 0.f, 0.f};
                z = __builtin_amdgcn_mfma_f32_16x16x32_bf16(aq[s][0], cur[kb][0], z, 0, 0, 0);
                z = __builtin_amdgcn_mfma_f32_16x16x32_bf16(aq[s][1], cur[kb][1], z, 0, 0, 0);
                sc[s][kb] = z;
            }
        }

        {
            int ktn = (kt + 1) & 15;
            #pragma unroll
            for (int kb = 0; kb < 4; kb++) {
                nxt[kb][0] = ks8[((long)ktn * 8 + kb * 2 + 0) * 64 + lane];
                nxt[kb][1] = ks8[((long)ktn * 8 + kb * 2 + 1) * 64 + lane];
            }
        }

        #pragma unroll
        for (int s = 0; s < 2; s++) {
            #pragma unroll
            for (int r = 0; r < 4; r++) {
                float p0 = __builtin_amdgcn_exp2f(sc[s][0][r]);
                float p1 = __builtin_amdgcn_exp2f(sc[s][1][r]);
                float p2 = __builtin_amdgcn_exp2f(sc[s][2][r]);
                float p3 = __builtin_amdgcn_exp2f(sc[s][3][r]);
                lsum[s][r] += (p0 + p1) + (p2 + p3);
                *(uint2*)&Pl[wave][s * 16 + quad * 4 + r][l16 * 4] =
                    make_uint2(pack_bf16rn(p0, p1), pack_bf16rn(p2, p3));
            }
        }

        #pragma unroll
        for (int ck = 0; ck < 2; ck++) {
            #pragma unroll
            for (int s = 0; s < 2; s++) {
                short8 ap = *(const short8*)&Pl[wave][s * 16 + l16][ck * 32 + quad * 8];
                #pragma unroll
                for (int cb = 0; cb < 4; cb++) {
                    O[s][cb] = __builtin_amdgcn_mfma_f32_16x16x32_bf16(ap, bvf[ck][cb], O[s][cb], 0, 0, 0);
                }
            }
        }
    };

    for (int kt = 0; kt < 16; kt += 2) {
        step(kt,     kfA, kfB);
        step(kt + 1, kfB, kfA);
    }

    #pragma unroll
    for (int s = 0; s < 2; s++)
        #pragma unroll
        for (int r = 0; r < 4; r++)
            #pragma unroll
            for (int off = 1; off < 16; off <<= 1)
                lsum[s][r] += __shfl_xor(lsum[s][r], off);

    // epilogue: per-strip f32 transpose via this wave's Pl slab -> vec stores
    float* fst = (float*)&Pl[wave][0][0];    // 4608 B >= 16*68*4 = 4352
    #pragma unroll
    for (int s = 0; s < 2; s++) {
        #pragma unroll
        for (int r = 0; r < 4; r++) {
            float rl = 1.0f / lsum[s][r];
            #pragma unroll
            for (int cb = 0; cb < 4; cb++)
                fst[(quad * 4 + r) * 68 + cb * 16 + l16] = O[s][cb][r] * rl;
        }
        #pragma unroll
        for (int j = 0; j < 4; j++) {
            int vidx = j * 64 + lane;
            int row = vidx >> 4, dp = (vidx & 15) * 4;
            f32x4 ov = *(const f32x4*)&fst[row * 68 + dp];
            long nrow = (long)b * Nsz + qbase + s * 16 + row;
            uint2 qv = *(const uint2*)(qs + nrow * Dsz + dp);
            ov[0] += bf2f((unsigned short)(qv.x)) * INV_SC;
            ov[1] += bf2f((unsigned short)(qv.x >> 16)) * INV_SC;
            ov[2] += bf2f((unsigned short)(qv.y)) * INV_SC;
            ov[3] += bf2f((unsigned short)(qv.y >> 16)) * INV_SC;
            *(f32x4*)(out + nrow * Dsz + dp) = ov;
        }
    }
}

extern "C" void kernel_launch(void* const* d_in, const int* in_sizes, int n_in,
                              void* d_out, int out_size, void* d_ws, size_t ws_size,
                              hipStream_t stream) {
    const float* x  = (const float*)d_in[0];
    const float* Wq = (const float*)d_in[1];
    const float* bq = (const float*)d_in[2];
    const float* Wk = (const float*)d_in[3];
    const float* bk = (const float*)d_in[4];
    const float* Wv = (const float*)d_in[5];
    const float* bv = (const float*)d_in[6];
    float* out = (float*)d_out;

    char* ws = (char*)d_ws;
    unsigned short* qsc   = (unsigned short*)ws;                 // 8 MB bf16 q*SC, [n][d]
    unsigned short* ks2   = (unsigned short*)(ws + 0x1000000);   // 8 MB bf16 K frag-major
    unsigned short* vt2   = (unsigned short*)(ws + 0x2000000);   // 8 MB bf16 V frag-major
    unsigned short* wfrag = (unsigned short*)(ws + 0x3000000);   // 48 KB W frags

    wprep_kernel<<<dim3(4), dim3(256), 0, stream>>>(Wq, Wk, Wv, wfrag);
    qkv_kernel<<<dim3(1024), dim3(256), 0, stream>>>(
        x, wfrag, bq, bk, bv, qsc, ks2, vt2);
    attn_kernel<<<dim3(512), dim3(256), 0, stream>>>(
        qsc, ks2, vt2, out);
}